// Round 21
// baseline (74.851 us; speedup 1.0000x reference)
//
#include <hip/hip_runtime.h>

// SpikeEncoder: out[b,h] = ( sum_k count[b,k]*W2[h,k] + S*T*b2[h] ) / B
// R21 = R20 + ONE merge: reduce_out folded into gemm2 via last-block-done.
// Writers: store part -> __threadfence() (agent release, buffer_wbl2) ->
// atomicAdd(flags[col-grp]). 16th block: __threadfence() (agent acquire,
// buffer_inv -> also clears replay-stale L2 lines) -> reduce (same kc order
// as reduce_out -> bit-identical). flags zeroed by lif (stream-ordered).
//
// ws: part[4MB) | cnt[256K) | flags[256B) | h1H[8MB) | Ahi(8M) Whi(2M)

#define TSTEPS 10
#define SEQ    64
#define BATCH  64
#define EDIM   1024
#define HDIM   1024
#define NROW   (SEQ * BATCH)   // 4096
#define KSPLIT 16

typedef unsigned short u16;
typedef __attribute__((ext_vector_type(8))) _Float16 half8;
typedef __attribute__((ext_vector_type(8))) unsigned short ushort8;
typedef __attribute__((ext_vector_type(4))) unsigned short ushort4v;
typedef __attribute__((ext_vector_type(4))) float  f32x4;

union h16 { _Float16 f; u16 u; };

__device__ __forceinline__ u16 f2h_bits(float x) {
    h16 t; t.f = (_Float16)x; return t.u;       // RNE
}
__device__ __forceinline__ float h2f(u16 b) {
    h16 t; t.u = b; return (float)t.f;
}
__device__ __forceinline__ void gld16(const u16* g, u16* l) {
    __builtin_amdgcn_global_load_lds(
        (const __attribute__((address_space(1))) void*)g,
        (__attribute__((address_space(3))) void*)l, 16, 0, 0);
}

// ---- pack fp32 -> fp16 (A gathered+permuted, W1) -------------------------
__global__ __launch_bounds__(256) void split_pack(
    const float* __restrict__ emb, const float* __restrict__ W1,
    const int* __restrict__ idx,
    u16* __restrict__ ahi, u16* __restrict__ whi)
{
    const int t = blockIdx.x * 256 + threadIdx.x;
    const int r = t >> 7;
    const int c = (t & 127) << 3;
    if (r < NROW) {
        const int srow = idx[(r & 63) * 64 + (r >> 6)];   // r = b*64+s
        const float* src = emb + (size_t)srow * EDIM + c;
        float4 v0 = *(const float4*)src;
        float4 v1 = *(const float4*)(src + 4);
        float x[8] = {v0.x, v0.y, v0.z, v0.w, v1.x, v1.y, v1.z, v1.w};
        ushort8 h;
#pragma unroll
        for (int j = 0; j < 8; ++j) h[j] = f2h_bits(x[j]);
        *(ushort8*)(ahi + (size_t)r * EDIM + c) = h;
    } else {
        const int rw = r - NROW;
        const float* src = W1 + (size_t)rw * EDIM + c;
        float4 v0 = *(const float4*)src;
        float4 v1 = *(const float4*)(src + 4);
        float x[8] = {v0.x, v0.y, v0.z, v0.w, v1.x, v1.y, v1.z, v1.w};
        ushort8 h;
#pragma unroll
        for (int j = 0; j < 8; ++j) h[j] = f2h_bits(x[j]);
        *(ushort8*)(whi + (size_t)rw * EDIM + c) = h;
    }
}

// ---- GEMM1 (R20 verbatim): 1-term fp16, 4-buf single-barrier, 3 blk/CU ---
#define BM 64
#define BN 128
#define BK 32
#define NT (EDIM / BK)
#define AH 0
#define WH 2048
#define BUF 6144      // 12KB in u16 units

__global__ __launch_bounds__(256, 3) void gemm1_h1(
    const u16* __restrict__ Ahi,
    const u16* __restrict__ Whi,
    u16* __restrict__ h1H)
{
    __shared__ float smf[12288];                // 48KB: 4x12KB staging
    u16* stage = (u16*)smf;

    const int bid = blockIdx.x;
    const int loc = bid >> 3;
    const int by  = (bid & 7) * 8 + (loc & 7);
    const int bx  = loc >> 3;
    const int row0 = by * BM, col0 = bx * BN;

    const int tid  = threadIdx.x;
    const int wave = tid >> 6, lane = tid & 63;
    const int wn   = wave;
    const int lrow = lane & 15, kgrp = lane >> 4;

    const int srr = lane >> 2;
    const int kcs = (((lane & 3) ^ ((lane >> 3) & 3)) << 3);
    const size_t aoff = (size_t)(row0 + wave * 16 + srr) * EDIM + kcs;
    const size_t w0   = (size_t)(col0 + wave * 32 + srr) * EDIM + kcs;
    const size_t w1   = w0 + (size_t)16 * EDIM;

    f32x4 acc[4][2];
    const f32x4 zero = {0.f, 0.f, 0.f, 0.f};
#pragma unroll
    for (int m = 0; m < 4; ++m)
#pragma unroll
        for (int n = 0; n < 2; ++n) acc[m][n] = zero;

    auto STAGE = [&](int k0, int b) {
        u16* lb = stage + b * BUF;
        gld16(Ahi + aoff + k0, lb + AH + wave * 512);
        gld16(Whi + w0 + k0, lb + WH + wave * 1024);
        gld16(Whi + w1 + k0, lb + WH + wave * 1024 + 512);
    };

    auto COMPUTE = [&](int b) {
        const u16* lb = stage + b * BUF;
        half8 ah[4], bh[2];
#pragma unroll
        for (int n = 0; n < 2; ++n) {
            const int c = wn * 32 + n * 16 + lrow;
            const int s = kgrp ^ ((c >> 1) & 3);
            bh[n] = *(const half8*)(lb + WH + c * 32 + s * 8);
        }
#pragma unroll
        for (int m = 0; m < 4; ++m) {
            const int r = m * 16 + lrow;
            const int s = kgrp ^ ((r >> 1) & 3);
            ah[m] = *(const half8*)(lb + AH + r * 32 + s * 8);
        }
#pragma unroll
        for (int m = 0; m < 4; ++m)
#pragma unroll
            for (int n = 0; n < 2; ++n)
                acc[m][n] = __builtin_amdgcn_mfma_f32_16x16x32_f16(ah[m], bh[n], acc[m][n], 0, 0, 0);
    };

    STAGE(0, 0);
    STAGE(BK, 1);
#pragma unroll 2
    for (int t = 0; t < NT - 2; ++t) {
        STAGE((t + 2) * BK, (t + 2) & 3);
        asm volatile("s_waitcnt vmcnt(6)" ::: "memory");
        __builtin_amdgcn_s_barrier();
        __builtin_amdgcn_sched_barrier(0);
        COMPUTE(t & 3);
    }
    asm volatile("s_waitcnt vmcnt(3)" ::: "memory");
    __builtin_amdgcn_s_barrier();
    __builtin_amdgcn_sched_barrier(0);
    COMPUTE((NT - 2) & 3);
    asm volatile("s_waitcnt vmcnt(0)" ::: "memory");
    __builtin_amdgcn_s_barrier();
    __builtin_amdgcn_sched_barrier(0);
    COMPUTE((NT - 1) & 3);

    // epilogue: h1H[b][k][s] fp16 straight from acc, ushort4 along s.
#pragma unroll
    for (int n = 0; n < 2; ++n) {
        const int col = col0 + wn * 32 + n * 16 + lrow;
        u16* base = h1H + ((size_t)by * HDIM + col) * 64 + kgrp * 4;
#pragma unroll
        for (int m = 0; m < 4; ++m) {
            ushort4v v;
#pragma unroll
            for (int j = 0; j < 4; ++j) v[j] = f2h_bits(acc[m][n][j]);
            *(ushort4v*)(base + m * 16) = v;
        }
    }
}

// ---- LIF (R20 + flags zeroing): 4-way sequence split ---------------------
__global__ __launch_bounds__(256) void lif_count(
    const u16* __restrict__ h1H,
    const float* __restrict__ bias1,
    const float* __restrict__ pthr, const float* __restrict__ pleak,
    float* __restrict__ cnt, int* __restrict__ flags)
{
    __shared__ float sm[4][64];
    const int tid  = threadIdx.x;
    if (blockIdx.x == 0 && tid < KSPLIT) flags[tid] = 0;  // replay-safe reset
    const int q    = tid >> 6;            // wave = sequence quarter
    const int lane = tid & 63;
    const int neuron = blockIdx.x * 64 + lane;
    const float thr = pthr[0];
    const float lk  = pleak[0];
    const float b1v = bias1[neuron & (HDIM - 1)];
    const u16* row = h1H + (size_t)neuron * 64;

    float mem = 0.f, c = 0.f;
    const int w0 = q * 16;                // first counted word
    if (q > 0) {
        ushort8 v = *(const ushort8*)(row + w0 - 8);   // warmup, uncounted
#pragma unroll
        for (int u = 0; u < 8; ++u) {
            const float x = h2f(v[u]) + b1v;
#pragma unroll
            for (int t = 0; t < TSTEPS; ++t) {
                mem = lk * mem + x;
                if (mem > thr) mem -= thr;
            }
        }
    }
#pragma unroll
    for (int g = 0; g < 2; ++g) {         // counted: 2 x 8 words
        ushort8 v = *(const ushort8*)(row + w0 + g * 8);
#pragma unroll
        for (int u = 0; u < 8; ++u) {
            const float x = h2f(v[u]) + b1v;
#pragma unroll
            for (int t = 0; t < TSTEPS; ++t) {
                mem = lk * mem + x;
                if (mem > thr) { c += 1.f; mem -= thr; }
            }
        }
    }
    sm[q][lane] = c;
    __syncthreads();
    if (tid < 64)
        cnt[(size_t)blockIdx.x * 64 + tid] =
            sm[0][tid] + sm[1][tid] + sm[2][tid] + sm[3][tid];
}

// ---- GEMM2 + fused last-block reduce --------------------------------------
__global__ __launch_bounds__(256) void gemm2_fused(
    const float* __restrict__ cnt,
    const float* __restrict__ W2,
    const float* __restrict__ b2,
    float* __restrict__ part,
    int* __restrict__ flags,
    float* __restrict__ out)
{
    __shared__ float As[32][68];
    __shared__ float Bs[32][68];
    __shared__ int lastFlag;

    const int tid   = threadIdx.x;
    const int colg  = blockIdx.x;          // 0..15 column group
    const int col0  = colg * 64;
    const int kc    = blockIdx.y;
    const int kbase = kc * 64;

    const int lr = tid >> 3;
    const int lc = (tid & 7) * 4;
    const int tm = (tid >> 4) * 4;
    const int tn = (tid & 15) * 4;

    float acc[4][4];
#pragma unroll
    for (int i = 0; i < 4; ++i)
#pragma unroll
        for (int j = 0; j < 4; ++j) acc[i][j] = 0.f;

    for (int kt = 0; kt < 2; ++kt) {
        const int k0 = kbase + kt * 32;
#pragma unroll
        for (int p = 0; p < 2; ++p) {
            int r = p * 32 + lr;
            float4 v = *(const float4*)(cnt + (size_t)r * HDIM + k0 + lc);
            As[lc + 0][r] = v.x; As[lc + 1][r] = v.y;
            As[lc + 2][r] = v.z; As[lc + 3][r] = v.w;
        }
#pragma unroll
        for (int p = 0; p < 2; ++p) {
            int r = p * 32 + lr;
            float4 v = *(const float4*)(W2 + (size_t)(col0 + r) * HDIM + k0 + lc);
            Bs[lc + 0][r] = v.x; Bs[lc + 1][r] = v.y;
            Bs[lc + 2][r] = v.z; Bs[lc + 3][r] = v.w;
        }
        __syncthreads();
#pragma unroll 8
        for (int k = 0; k < 32; ++k) {
            float4 a  = *(const float4*)&As[k][tm];
            float4 bb = *(const float4*)&Bs[k][tn];
            float av[4] = {a.x, a.y, a.z, a.w};
            float bv[4] = {bb.x, bb.y, bb.z, bb.w};
#pragma unroll
            for (int i = 0; i < 4; ++i)
#pragma unroll
                for (int j = 0; j < 4; ++j)
                    acc[i][j] += av[i] * bv[j];
        }
        __syncthreads();
    }

#pragma unroll
    for (int i = 0; i < 4; ++i) {
        float* prow = part + (size_t)kc * (BATCH * HDIM) + (size_t)(tm + i) * HDIM + col0;
        float4 o;
        o.x = acc[i][0]; o.y = acc[i][1]; o.z = acc[i][2]; o.w = acc[i][3];
        *(float4*)(prow + tn) = o;
    }

    // release: flush part stores to coherence point, then signal.
    __threadfence();
    if (tid == 0)
        lastFlag = atomicAdd(&flags[colg], 1);
    __syncthreads();
    if (lastFlag != KSPLIT - 1) return;

    // acquire: invalidate local L2 so part reads see all writers (and no
    // replay-stale lines), then reduce this column group (same kc order as
    // the old reduce_out -> bit-identical).
    __threadfence();
#pragma unroll
    for (int i = 0; i < 16; ++i) {
        const int idx = i * 256 + tid;         // 0..4095
        const int b   = idx >> 6;
        const int c   = idx & 63;
        float s = 0.f;
#pragma unroll
        for (int k2 = 0; k2 < KSPLIT; ++k2)
            s += part[(size_t)k2 * (BATCH * HDIM) + (size_t)b * HDIM + col0 + c];
        out[(size_t)b * HDIM + col0 + c] =
            (s + (float)(SEQ * TSTEPS) * b2[col0 + c]) * (1.0f / (float)BATCH);
    }
}

extern "C" void kernel_launch(void* const* d_in, const int* in_sizes, int n_in,
                              void* d_out, int out_size, void* d_ws, size_t ws_size,
                              hipStream_t stream)
{
    (void)in_sizes; (void)n_in; (void)out_size; (void)ws_size;

    const int*   idx  = (const int*)d_in[0];
    const float* emb  = (const float*)d_in[1];
    const float* W1   = (const float*)d_in[2];
    const float* b1   = (const float*)d_in[3];
    const float* W2   = (const float*)d_in[4];
    const float* b2   = (const float*)d_in[5];
    const float* thr  = (const float*)d_in[6];
    const float* leak = (const float*)d_in[7];
    float* out = (float*)d_out;

    char* ws = (char*)d_ws;
    float* part  = (float*)ws;                                       // 4 MB
    float* cnt   = (float*)(ws + (size_t)KSPLIT * BATCH * HDIM * 4); // 256 KB
    int*   flags = (int*)(cnt + (size_t)BATCH * HDIM);               // 256 B
    u16*   h1H   = (u16*)((char*)flags + 256);                       // 8 MB
    u16* ahi = h1H + (size_t)NROW * HDIM;                            // 8 MB
    u16* whi = ahi + (size_t)NROW * EDIM;                            // 2 MB

    split_pack<<<dim3((NROW + HDIM) * 128 / 256), 256, 0, stream>>>(
        emb, W1, idx, ahi, whi);

    gemm1_h1<<<dim3((NROW / BM) * (HDIM / BN)), 256, 0, stream>>>(
        ahi, whi, h1H);

    lif_count<<<dim3(BATCH * HDIM / 64), 256, 0, stream>>>(
        h1H, b1, thr, leak, cnt, flags);

    gemm2_fused<<<dim3(HDIM / 64, KSPLIT), 256, 0, stream>>>(
        cnt, W2, b2, part, flags, out);
}

// Round 22
// 45.318 us; speedup vs baseline: 1.6517x; 1.6517x over previous
//
#include <hip/hip_runtime.h>

// SpikeEncoder: out[b,h] = ( sum_k count[b,k]*W2[h,k] + S*T*b2[h] ) / B
// R22 = R20 VERBATIM (measured best, 45.33us). R21's fence-based reduce
// fusion regressed +29.5us (L2 flush storm from per-block __threadfence on
// non-coherent XCDs) -> reverted. Kernel-boundary implicit flush is the
// cheapest cross-stage visibility mechanism on this chip (R8/R19/R21).
//
// ws: part[4MB) | cnt[256K) | h1H[8MB fp16) | Ahi(8M) Whi(2M)

#define TSTEPS 10
#define SEQ    64
#define BATCH  64
#define EDIM   1024
#define HDIM   1024
#define NROW   (SEQ * BATCH)   // 4096
#define KSPLIT 16

typedef unsigned short u16;
typedef __attribute__((ext_vector_type(8))) _Float16 half8;
typedef __attribute__((ext_vector_type(8))) unsigned short ushort8;
typedef __attribute__((ext_vector_type(4))) unsigned short ushort4v;
typedef __attribute__((ext_vector_type(4))) float  f32x4;

union h16 { _Float16 f; u16 u; };

__device__ __forceinline__ u16 f2h_bits(float x) {
    h16 t; t.f = (_Float16)x; return t.u;       // RNE
}
__device__ __forceinline__ float h2f(u16 b) {
    h16 t; t.u = b; return (float)t.f;
}
__device__ __forceinline__ void gld16(const u16* g, u16* l) {
    __builtin_amdgcn_global_load_lds(
        (const __attribute__((address_space(1))) void*)g,
        (__attribute__((address_space(3))) void*)l, 16, 0, 0);
}

// ---- pack fp32 -> fp16 (A gathered+permuted, W1) -------------------------
__global__ __launch_bounds__(256) void split_pack(
    const float* __restrict__ emb, const float* __restrict__ W1,
    const int* __restrict__ idx,
    u16* __restrict__ ahi, u16* __restrict__ whi)
{
    const int t = blockIdx.x * 256 + threadIdx.x;
    const int r = t >> 7;
    const int c = (t & 127) << 3;
    if (r < NROW) {
        const int srow = idx[(r & 63) * 64 + (r >> 6)];   // r = b*64+s
        const float* src = emb + (size_t)srow * EDIM + c;
        float4 v0 = *(const float4*)src;
        float4 v1 = *(const float4*)(src + 4);
        float x[8] = {v0.x, v0.y, v0.z, v0.w, v1.x, v1.y, v1.z, v1.w};
        ushort8 h;
#pragma unroll
        for (int j = 0; j < 8; ++j) h[j] = f2h_bits(x[j]);
        *(ushort8*)(ahi + (size_t)r * EDIM + c) = h;
    } else {
        const int rw = r - NROW;
        const float* src = W1 + (size_t)rw * EDIM + c;
        float4 v0 = *(const float4*)src;
        float4 v1 = *(const float4*)(src + 4);
        float x[8] = {v0.x, v0.y, v0.z, v0.w, v1.x, v1.y, v1.z, v1.w};
        ushort8 h;
#pragma unroll
        for (int j = 0; j < 8; ++j) h[j] = f2h_bits(x[j]);
        *(ushort8*)(whi + (size_t)rw * EDIM + c) = h;
    }
}

// ---- GEMM1: 1-term fp16, 4-buf single-barrier, counted vmcnt, 3 blk/CU ---
#define BM 64
#define BN 128
#define BK 32
#define NT (EDIM / BK)
#define AH 0
#define WH 2048
#define BUF 6144      // 12KB in u16 units

__global__ __launch_bounds__(256, 3) void gemm1_h1(
    const u16* __restrict__ Ahi,
    const u16* __restrict__ Whi,
    u16* __restrict__ h1H)
{
    __shared__ float smf[12288];                // 48KB: 4x12KB staging
    u16* stage = (u16*)smf;

    const int bid = blockIdx.x;
    const int loc = bid >> 3;
    const int by  = (bid & 7) * 8 + (loc & 7);
    const int bx  = loc >> 3;
    const int row0 = by * BM, col0 = bx * BN;

    const int tid  = threadIdx.x;
    const int wave = tid >> 6, lane = tid & 63;
    const int wn   = wave;
    const int lrow = lane & 15, kgrp = lane >> 4;

    const int srr = lane >> 2;
    const int kcs = (((lane & 3) ^ ((lane >> 3) & 3)) << 3);
    const size_t aoff = (size_t)(row0 + wave * 16 + srr) * EDIM + kcs;
    const size_t w0   = (size_t)(col0 + wave * 32 + srr) * EDIM + kcs;
    const size_t w1   = w0 + (size_t)16 * EDIM;

    f32x4 acc[4][2];
    const f32x4 zero = {0.f, 0.f, 0.f, 0.f};
#pragma unroll
    for (int m = 0; m < 4; ++m)
#pragma unroll
        for (int n = 0; n < 2; ++n) acc[m][n] = zero;

    // per-thread gld16 count per STAGE = 3 (vmcnt accounting)
    auto STAGE = [&](int k0, int b) {
        u16* lb = stage + b * BUF;
        gld16(Ahi + aoff + k0, lb + AH + wave * 512);
        gld16(Whi + w0 + k0, lb + WH + wave * 1024);
        gld16(Whi + w1 + k0, lb + WH + wave * 1024 + 512);
    };

    auto COMPUTE = [&](int b) {
        const u16* lb = stage + b * BUF;
        half8 ah[4], bh[2];
#pragma unroll
        for (int n = 0; n < 2; ++n) {
            const int c = wn * 32 + n * 16 + lrow;
            const int s = kgrp ^ ((c >> 1) & 3);
            bh[n] = *(const half8*)(lb + WH + c * 32 + s * 8);
        }
#pragma unroll
        for (int m = 0; m < 4; ++m) {
            const int r = m * 16 + lrow;
            const int s = kgrp ^ ((r >> 1) & 3);
            ah[m] = *(const half8*)(lb + AH + r * 32 + s * 8);
        }
#pragma unroll
        for (int m = 0; m < 4; ++m)
#pragma unroll
            for (int n = 0; n < 2; ++n)
                acc[m][n] = __builtin_amdgcn_mfma_f32_16x16x32_f16(ah[m], bh[n], acc[m][n], 0, 0, 0);
    };

    // 4 buffers, depth-2 prefetch, ONE barrier per step (R5 ledger):
    // between barriers, only COMPUTE(t) [reads buf t&3] and STAGE(t+2)
    // [writes buf (t+2)&3] are in flight; buf (t+2)&3's readers were
    // COMPUTE(t-2), complete before barrier(t-1).
    STAGE(0, 0);
    STAGE(BK, 1);
#pragma unroll 2
    for (int t = 0; t < NT - 2; ++t) {
        STAGE((t + 2) * BK, (t + 2) & 3);
        asm volatile("s_waitcnt vmcnt(6)" ::: "memory");
        __builtin_amdgcn_s_barrier();
        __builtin_amdgcn_sched_barrier(0);
        COMPUTE(t & 3);
    }
    asm volatile("s_waitcnt vmcnt(3)" ::: "memory");
    __builtin_amdgcn_s_barrier();
    __builtin_amdgcn_sched_barrier(0);
    COMPUTE((NT - 2) & 3);
    asm volatile("s_waitcnt vmcnt(0)" ::: "memory");
    __builtin_amdgcn_s_barrier();
    __builtin_amdgcn_sched_barrier(0);
    COMPUTE((NT - 1) & 3);

    // epilogue: h1H[b][k][s] fp16 straight from acc, ushort4 along s.
#pragma unroll
    for (int n = 0; n < 2; ++n) {
        const int col = col0 + wn * 32 + n * 16 + lrow;
        u16* base = h1H + ((size_t)by * HDIM + col) * 64 + kgrp * 4;
#pragma unroll
        for (int m = 0; m < 4; ++m) {
            ushort4v v;
#pragma unroll
            for (int j = 0; j < 4; ++j) v[j] = f2h_bits(acc[m][n][j]);
            *(ushort4v*)(base + m * 16) = v;
        }
    }
}

// ---- LIF: 4-way sequence split, fp16 input --------------------------------
__global__ __launch_bounds__(256) void lif_count(
    const u16* __restrict__ h1H,
    const float* __restrict__ bias1,
    const float* __restrict__ pthr, const float* __restrict__ pleak,
    float* __restrict__ cnt)
{
    __shared__ float sm[4][64];
    const int tid  = threadIdx.x;
    const int q    = tid >> 6;            // wave = sequence quarter
    const int lane = tid & 63;
    const int neuron = blockIdx.x * 64 + lane;
    const float thr = pthr[0];
    const float lk  = pleak[0];
    const float b1v = bias1[neuron & (HDIM - 1)];
    const u16* row = h1H + (size_t)neuron * 64;

    float mem = 0.f, c = 0.f;
    const int w0 = q * 16;                // first counted word
    if (q > 0) {
        ushort8 v = *(const ushort8*)(row + w0 - 8);   // warmup, uncounted
#pragma unroll
        for (int u = 0; u < 8; ++u) {
            const float x = h2f(v[u]) + b1v;
#pragma unroll
            for (int t = 0; t < TSTEPS; ++t) {
                mem = lk * mem + x;
                if (mem > thr) mem -= thr;
            }
        }
    }
#pragma unroll
    for (int g = 0; g < 2; ++g) {         // counted: 2 x 8 words
        ushort8 v = *(const ushort8*)(row + w0 + g * 8);
#pragma unroll
        for (int u = 0; u < 8; ++u) {
            const float x = h2f(v[u]) + b1v;
#pragma unroll
            for (int t = 0; t < TSTEPS; ++t) {
                mem = lk * mem + x;
                if (mem > thr) { c += 1.f; mem -= thr; }
            }
        }
    }
    sm[q][lane] = c;
    __syncthreads();
    if (tid < 64)
        cnt[(size_t)blockIdx.x * 64 + tid] =
            sm[0][tid] + sm[1][tid] + sm[2][tid] + sm[3][tid];
}

// ---- GEMM2: K-split partials, 64-col tiles (256 blocks) -------------------
__global__ __launch_bounds__(256) void gemm2_partial(
    const float* __restrict__ cnt,
    const float* __restrict__ W2,
    float* __restrict__ part)
{
    __shared__ float As[32][68];
    __shared__ float Bs[32][68];

    const int tid   = threadIdx.x;
    const int col0  = blockIdx.x * 64;
    const int kc    = blockIdx.y;
    const int kbase = kc * 64;

    const int lr = tid >> 3;
    const int lc = (tid & 7) * 4;
    const int tm = (tid >> 4) * 4;
    const int tn = (tid & 15) * 4;

    float acc[4][4];
#pragma unroll
    for (int i = 0; i < 4; ++i)
#pragma unroll
        for (int j = 0; j < 4; ++j) acc[i][j] = 0.f;

    for (int kt = 0; kt < 2; ++kt) {
        const int k0 = kbase + kt * 32;
#pragma unroll
        for (int p = 0; p < 2; ++p) {
            int r = p * 32 + lr;
            float4 v = *(const float4*)(cnt + (size_t)r * HDIM + k0 + lc);
            As[lc + 0][r] = v.x; As[lc + 1][r] = v.y;
            As[lc + 2][r] = v.z; As[lc + 3][r] = v.w;
        }
#pragma unroll
        for (int p = 0; p < 2; ++p) {
            int r = p * 32 + lr;
            float4 v = *(const float4*)(W2 + (size_t)(col0 + r) * HDIM + k0 + lc);
            Bs[lc + 0][r] = v.x; Bs[lc + 1][r] = v.y;
            Bs[lc + 2][r] = v.z; Bs[lc + 3][r] = v.w;
        }
        __syncthreads();
#pragma unroll 8
        for (int k = 0; k < 32; ++k) {
            float4 a  = *(const float4*)&As[k][tm];
            float4 bb = *(const float4*)&Bs[k][tn];
            float av[4] = {a.x, a.y, a.z, a.w};
            float bv[4] = {bb.x, bb.y, bb.z, bb.w};
#pragma unroll
            for (int i = 0; i < 4; ++i)
#pragma unroll
                for (int j = 0; j < 4; ++j)
                    acc[i][j] += av[i] * bv[j];
        }
        __syncthreads();
    }

#pragma unroll
    for (int i = 0; i < 4; ++i) {
        float* prow = part + (size_t)kc * (BATCH * HDIM) + (size_t)(tm + i) * HDIM + col0;
        float4 o;
        o.x = acc[i][0]; o.y = acc[i][1]; o.z = acc[i][2]; o.w = acc[i][3];
        *(float4*)(prow + tn) = o;
    }
}

// ---- final reduce: out = (sum_kc part + 640*b2) / 64 ----------------------
__global__ __launch_bounds__(256) void reduce_out(
    const float* __restrict__ part,
    const float* __restrict__ b2,
    float* __restrict__ out)
{
    const int i = blockIdx.x * 256 + threadIdx.x;
    float s = 0.f;
#pragma unroll
    for (int kc = 0; kc < KSPLIT; ++kc)
        s += part[(size_t)kc * (BATCH * HDIM) + i];
    const int h = i & (HDIM - 1);
    out[i] = (s + (float)(SEQ * TSTEPS) * b2[h]) * (1.0f / (float)BATCH);
}

extern "C" void kernel_launch(void* const* d_in, const int* in_sizes, int n_in,
                              void* d_out, int out_size, void* d_ws, size_t ws_size,
                              hipStream_t stream)
{
    (void)in_sizes; (void)n_in; (void)out_size; (void)ws_size;

    const int*   idx  = (const int*)d_in[0];
    const float* emb  = (const float*)d_in[1];
    const float* W1   = (const float*)d_in[2];
    const float* b1   = (const float*)d_in[3];
    const float* W2   = (const float*)d_in[4];
    const float* b2   = (const float*)d_in[5];
    const float* thr  = (const float*)d_in[6];
    const float* leak = (const float*)d_in[7];
    float* out = (float*)d_out;

    char* ws = (char*)d_ws;
    float* part = (float*)ws;                                        // 4 MB
    float* cnt  = (float*)(ws + (size_t)KSPLIT * BATCH * HDIM * 4);  // 256 KB
    u16*   h1H  = (u16*)(cnt + (size_t)BATCH * HDIM);                // 8 MB
    u16* ahi = h1H + (size_t)NROW * HDIM;                            // 8 MB
    u16* whi = ahi + (size_t)NROW * EDIM;                            // 2 MB

    split_pack<<<dim3((NROW + HDIM) * 128 / 256), 256, 0, stream>>>(
        emb, W1, idx, ahi, whi);

    gemm1_h1<<<dim3((NROW / BM) * (HDIM / BN)), 256, 0, stream>>>(
        ahi, whi, h1H);

    lif_count<<<dim3(BATCH * HDIM / 64), 256, 0, stream>>>(
        h1H, b1, thr, leak, cnt);

    gemm2_partial<<<dim3(HDIM / 64, KSPLIT), 256, 0, stream>>>(cnt, W2, part);

    reduce_out<<<dim3((BATCH * HDIM) / 256), 256, 0, stream>>>(part, b2, out);
}